// Round 6
// baseline (314.424 us; speedup 1.0000x reference)
//
#include <hip/hip_runtime.h>
#include <math.h>

// RWKV-6 chunked scan, T-split edition.  B=4 H=32 T=2048 K=V=64.
// Kernel A: 512 blocks = (g t-half) x (vh v-half) x (bh), 512 thr, 2 blocks/CU.
//   Each block walks 16 chunks of its half with the round-5 2-barrier pipeline
//   (SEG1: pass1(c+1) || A-tiles(c);  SEG2: pass2(c+1) || prefetch(c+2) ||
//    o(c)+S_c(c) || state).  Half g=1 starts from h0=0 and streams
//    Qt[t][k] = q*e^{local cw_{t-1}} (bf16) to workspace; g=0 writes h_mid.
// Kernel B: o[second half] += Qt . h_mid  (rank-64 MFMA correction, RMW-in-acc).
// Kernel C: fin = h_end + e^{sumw_half2} * h_mid.
// Linearity of the scan in h makes this exact; correction is the same bf16
// rounding class as the in-kernel Qh*Ht term.
// Numerics per chunk unchanged from the verified kernel:
//   Qh = q*e^{cw_{t-1}-Cmid}, Kh = k*e^{Cmid-cw_s}  (Cmid = cw_31)
//   A-diag = q*u*k;  S_c scaled by e^{tot-Cmid} per-k;  h = h*e^{tot} + S_c.

#define Bdim 4
#define Hdim 32
#define Tdim 2048
#define Kdim 64
#define Vdim 64
#define NCH  16   // chunks per half
#define CL   64
#define LP   72   // padded LDS row stride (bf16): 144 B = 9 x 16 B (bank-uniform b128)

typedef __attribute__((ext_vector_type(8))) short short8;
typedef __attribute__((ext_vector_type(4))) short short4_;
typedef __attribute__((ext_vector_type(4))) float float4_;

__device__ __forceinline__ short f2bf(float x) {
    unsigned u = __float_as_uint(x);
    unsigned r = (u + 0x7FFFu + ((u >> 16) & 1u)) >> 16;
    return (short)r;
}

#define MFMA(a, b, c) __builtin_amdgcn_mfma_f32_16x16x32_bf16(a, b, c, 0, 0, 0)

// Barrier WITHOUT the vmcnt(0) drain __syncthreads emits: LDS producer
// visibility only; global prefetch loads stay in flight across it.
__device__ __forceinline__ void wg_barrier() {
    __builtin_amdgcn_sched_barrier(0);
    asm volatile("s_waitcnt lgkmcnt(0)");
    __builtin_amdgcn_s_barrier();
    __builtin_amdgcn_sched_barrier(0);
}

__global__ __launch_bounds__(512) void rwkv6_halves(
    const float* __restrict__ rin, const float* __restrict__ kin,
    const float* __restrict__ vin, const float* __restrict__ win,
    const float* __restrict__ uin, const float* __restrict__ init,
    float* __restrict__ oout,
    unsigned short* __restrict__ qtg, float* __restrict__ hmid,
    float* __restrict__ hend, float* __restrict__ sumw)
{
    __shared__ __attribute__((aligned(16))) short Qh[2][CL * LP];
    __shared__ __attribute__((aligned(16))) short Kh[CL * LP];      // [s][k], single
    __shared__ __attribute__((aligned(16))) short KhT[2][CL * LP];  // [k][s]
    __shared__ __attribute__((aligned(16))) short Am[CL * LP];      // single
    __shared__ __attribute__((aligned(16))) short Vt[2][32 * LP];   // V^T[v_local][s]
    __shared__ __attribute__((aligned(16))) short Ht[2][32 * LP];   // (h*e^{Cmid})^T[v][k]
    __shared__ float bsum[2][8 * 64];
    __shared__ float Dd[CL];

    const int tid  = threadIdx.x;
    const int wv   = tid >> 6;          // wave 0..7
    const int lane = tid & 63;          // k index in preprocessing
    const int quad = lane >> 4, r = lane & 15;

    const int bid = blockIdx.x;
    const int g   = bid >> 8;           // t-half 0/1
    const int vh  = (bid >> 7) & 1;     // v-half 0/1
    const int bh  = bid & 127;
    const int h_idx = bh & (Hdim - 1);

    // S_c/state mapping: wave -> (v-tile m_s, k-tile n_s)
    const int m_s = wv >> 2;            // 0..1
    const int n_s = wv & 3;             // 0..3
    const int k_  = 16 * n_s + r;       // this thread's k column of the state
    // o-phase mapping: wave -> (t-tile i_o, v-tile n_o)
    const int i_o = wv >> 1;            // 0..3
    const int n_o = wv & 1;             // 0..1

    const float u_ = uin[h_idx * Kdim + lane];

    // V staging: thread owns v-row svrow, 4 consecutive s-cols
    const int svrow = tid & 31;         // v_local 0..31
    const int skq   = tid >> 5;         // 0..15 -> s cols 4*skq .. 4*skq+3

    // ---- zero Am (upper triangle stays 0 forever) ----
    for (int i = tid; i < CL * LP; i += 512) Am[i] = 0;

    // prefetch registers
    float wl[8], ql[8], kl[8], vls[4];
    float cwacc = 0.f;                  // per-lane (k=lane) running half-local cw

    auto do_prefetch = [&](size_t nb) {
#pragma unroll
        for (int tt = 0; tt < 8; ++tt) wl[tt] = win[nb + (8 * wv + tt) * Kdim + lane];
#pragma unroll
        for (int i = 0; i < 4; ++i)
            vls[i] = vin[nb + (4 * skq + i) * Kdim + 32 * vh + svrow];
#pragma unroll
        for (int tt = 0; tt < 8; ++tt) ql[tt] = rin[nb + (8 * wv + tt) * Kdim + lane];
#pragma unroll
        for (int tt = 0; tt < 8; ++tt) kl[tt] = kin[nb + (8 * wv + tt) * Kdim + lane];
    };

    auto do_pass1 = [&](int Y) {
        float cwl = 0.f;
#pragma unroll
        for (int tt = 0; tt < 8; ++tt) cwl += wl[tt];
        bsum[Y][wv * 64 + lane] = cwl;
        short4_ pack;
#pragma unroll
        for (int i = 0; i < 4; ++i) pack[i] = f2bf(vls[i]);
        *(short4_*)&Vt[Y][svrow * LP + 4 * skq] = pack;
    };

    // stages chunk cloc (half-local index) into buffer Y; tracks cwacc
    auto do_pass2 = [&](int Y, int cloc) {
        float b8[8];
#pragma unroll
        for (int j = 0; j < 8; ++j) b8[j] = bsum[Y][j * 64 + lane];
        float pref = 0.f;
#pragma unroll
        for (int j = 0; j < 8; ++j) if (j < wv) pref += b8[j];
        const float Cmid = b8[0] + b8[1] + b8[2] + b8[3];        // cw_31 (chunk-local)
        const float tot  = Cmid + b8[4] + b8[5] + b8[6] + b8[7];
        float cwrun = pref;                                      // cw_{t-1} entering block
        short8 khrow;
        float d3p[8];
#pragma unroll
        for (int tt = 0; tt < 8; ++tt) {
            const int t = 8 * wv + tt;
            const float cwp = cwrun;                             // cw_{t-1}
            cwrun += wl[tt];                                     // cw_t
            Qh[Y][t * LP + lane] = f2bf(ql[tt] * __expf(cwp - Cmid));
            const short kv = f2bf(kl[tt] * __expf(Cmid - cwrun));
            Kh[t * LP + lane] = kv;
            khrow[tt] = kv;
            d3p[tt] = ql[tt] * u_ * kl[tt];
            if (g) {                                             // Qt for correction GEMM
                qtg[((size_t)bh * 1024 + (size_t)cloc * CL + t) * Kdim + lane]
                    = (unsigned short)f2bf(ql[tt] * __expf(cwacc + cwp));
            }
        }
        cwacc += tot;
        *(short8*)&KhT[Y][lane * LP + wv * 8] = khrow;           // transposed b128
#pragma unroll
        for (int off = 32; off > 0; off >>= 1) {                 // batched reduce, 8-wide ILP
#pragma unroll
            for (int tt = 0; tt < 8; ++tt) d3p[tt] += __shfl_xor(d3p[tt], off);
        }
        if (lane == 0) {
#pragma unroll
            for (int tt = 0; tt < 8; ++tt) Dd[8 * wv + tt] = d3p[tt];
        }
    };

    auto atile = [&](int X, int i, int j) {
        const int trow = 16 * i + r;
        short8 qa0 = *(const short8*)&Qh[X][trow * LP + quad * 8];
        short8 qa1 = *(const short8*)&Qh[X][trow * LP + 32 + quad * 8];
        const int srow = 16 * j + r;
        short8 kb0 = *(const short8*)&Kh[srow * LP + quad * 8];
        short8 kb1 = *(const short8*)&Kh[srow * LP + 32 + quad * 8];
        float4_ acc = {0.f, 0.f, 0.f, 0.f};
        acc = MFMA(qa0, kb0, acc);
        acc = MFMA(qa1, kb1, acc);
#pragma unroll
        for (int reg = 0; reg < 4; ++reg) {
            const int tg = 16 * i + quad * 4 + reg;
            const float val = (tg > srow) ? acc[reg] : ((tg == srow) ? Dd[tg] : 0.f);
            Am[tg * LP + srow] = f2bf(val);
        }
    };

    // ================= prologue =================
    const size_t half_base = (size_t)bh * Tdim * Kdim + (size_t)g * (Tdim / 2) * Kdim;
    do_prefetch(half_base);                     // chunk 0
    do_pass1(0);
    wg_barrier();
    do_pass2(0, 0);
    float h[4];
    {   // h init (g=0: true init; g=1: zero) + Ht[0] = h * e^{Cmid(0)}
        const float cm0 = bsum[0][0 * 64 + k_] + bsum[0][64 + k_]
                        + bsum[0][128 + k_] + bsum[0][192 + k_];
        const float eH = __expf(cm0);
#pragma unroll
        for (int reg = 0; reg < 4; ++reg) {
            const int vloc = 16 * m_s + quad * 4 + reg;
            h[reg] = g ? 0.f
                       : init[((size_t)bh * Kdim + k_) * Vdim + 32 * vh + vloc];
            Ht[0][vloc * LP + k_] = f2bf(h[reg] * eH);
        }
    }
    do_prefetch(half_base + (size_t)CL * Kdim); // chunk 1
    wg_barrier();

    // ================= main loop: 2 barriers/chunk =================
    for (int c = 0; c < NCH; ++c) {
        const int X = c & 1, Y = X ^ 1;
        const size_t base = half_base + (size_t)c * CL * Kdim;

        // ---- SEG1: pass1(c+1) || A-tiles(c) ----
        if (c + 1 < NCH) do_pass1(Y);
        __builtin_amdgcn_s_setprio(1);
        {
            int i0, j0;
            if (wv == 0)      { i0 = 0; j0 = 0; }
            else if (wv < 3)  { i0 = 1; j0 = wv - 1; }
            else if (wv < 6)  { i0 = 2; j0 = wv - 3; }
            else              { i0 = 3; j0 = wv - 6; }
            atile(X, i0, j0);
            if (wv < 2) atile(X, 3, 2 + wv);                    // tiles (3,2),(3,3)
        }
        __builtin_amdgcn_s_setprio(0);
        wg_barrier();                                           // alpha

        // ---- SEG2: pass2(c+1) || prefetch(c+2) || o(c)+S_c(c) || state ----
        if (c + 1 < NCH) do_pass2(Y, c + 1);
        if (c + 2 < NCH) do_prefetch(half_base + (size_t)(c + 2) * CL * Kdim);

        __builtin_amdgcn_s_setprio(1);
        {   // o-phase: o = Am.V + Qh.Ht'
            const int trow = 16 * i_o + r;
            short8 aa0 = *(const short8*)&Am[trow * LP + quad * 8];
            short8 aa1 = *(const short8*)&Am[trow * LP + 32 + quad * 8];
            short8 qh0 = *(const short8*)&Qh[X][trow * LP + quad * 8];
            short8 qh1 = *(const short8*)&Qh[X][trow * LP + 32 + quad * 8];
            const int vrow = 16 * n_o + r;
            short8 vb0 = *(const short8*)&Vt[X][vrow * LP + quad * 8];
            short8 vb1 = *(const short8*)&Vt[X][vrow * LP + 32 + quad * 8];
            short8 hb0 = *(const short8*)&Ht[X][vrow * LP + quad * 8];
            short8 hb1 = *(const short8*)&Ht[X][vrow * LP + 32 + quad * 8];
            float4_ o4 = {0.f, 0.f, 0.f, 0.f};
            o4 = MFMA(aa0, vb0, o4);
            o4 = MFMA(aa1, vb1, o4);
            o4 = MFMA(qh0, hb0, o4);
            o4 = MFMA(qh1, hb1, o4);
            float* op = oout + base;
#pragma unroll
            for (int reg = 0; reg < 4; ++reg)
                op[(16 * i_o + quad * 4 + reg) * Vdim + 32 * vh + 16 * n_o + r] = o4[reg];
        }
        float4_ sc = {0.f, 0.f, 0.f, 0.f};
        {   // S_c: D[v][k] = sum_s V[s][v]*Khat[s][k]
            const int vrow = 16 * m_s + r;
            short8 va0 = *(const short8*)&Vt[X][vrow * LP + quad * 8];
            short8 va1 = *(const short8*)&Vt[X][vrow * LP + 32 + quad * 8];
            short8 kc0 = *(const short8*)&KhT[X][k_ * LP + quad * 8];
            short8 kc1 = *(const short8*)&KhT[X][k_ * LP + 32 + quad * 8];
            sc = MFMA(va0, kc0, sc);
            sc = MFMA(va1, kc1, sc);
        }
        __builtin_amdgcn_s_setprio(0);

        // ---- state update ----
        {
            float totk = 0.f, cmk = 0.f;
#pragma unroll
            for (int j = 0; j < 8; ++j) {
                const float bb = bsum[X][j * 64 + k_];
                totk += bb;
                if (j < 4) cmk += bb;
            }
            const float eA = __expf(totk);                       // e^{cw_63}
            const float eS = __expf(totk - cmk);                 // Khat-acc -> Kbar-acc
#pragma unroll
            for (int reg = 0; reg < 4; ++reg)
                h[reg] = h[reg] * eA + sc[reg] * eS;
            if (c + 1 < NCH) {                                   // Ht' for chunk c+1
                const float cm1 = bsum[Y][0 * 64 + k_] + bsum[Y][64 + k_]
                                + bsum[Y][128 + k_] + bsum[Y][192 + k_];
                const float eH = __expf(cm1);
#pragma unroll
                for (int reg = 0; reg < 4; ++reg)
                    Ht[Y][(16 * m_s + quad * 4 + reg) * LP + k_] = f2bf(h[reg] * eH);
            }
        }
        wg_barrier();                                           // beta
    }

    // ---- half-final state to workspace ----
    if (g == 0) {
#pragma unroll
        for (int reg = 0; reg < 4; ++reg)
            hmid[((size_t)bh * 64 + 32 * vh + 16 * m_s + quad * 4 + reg) * 64 + k_] = h[reg];
    } else {
#pragma unroll
        for (int reg = 0; reg < 4; ++reg)
            hend[((size_t)bh * 64 + 32 * vh + 16 * m_s + quad * 4 + reg) * 64 + k_] = h[reg];
        if (vh == 0 && wv == 0) sumw[bh * 64 + lane] = cwacc;    // per-lane, wave-uniform
    }
}

// ---- Kernel B: o[t in half2] += Qt[t] . h_mid   (1024 blocks, 4 waves) ----
__global__ __launch_bounds__(256) void rwkv6_fix(
    const unsigned short* __restrict__ qtg, const float* __restrict__ hmid,
    float* __restrict__ oout)
{
    __shared__ __attribute__((aligned(16))) short Hm[64 * LP];   // bf16 [v][k]
    const int tid = threadIdx.x;
    const int wv = tid >> 6, lane = tid & 63;
    const int quad = lane >> 4, r = lane & 15;
    const int bid = blockIdx.x;
    const int bh = bid >> 3, slab = bid & 7;

    const float* hm = hmid + (size_t)bh * 4096;
    for (int i = tid; i < 4096; i += 256)
        Hm[(i >> 6) * LP + (i & 63)] = f2bf(hm[i]);
    __syncthreads();

#pragma unroll
    for (int ti = 0; ti < 2; ++ti) {
        const int tl0 = slab * 128 + (wv * 2 + ti) * 16;         // half-local tile base
        const unsigned short* qrow = qtg + ((size_t)bh * 1024 + tl0 + r) * Kdim;
        short8 qa0 = *(const short8*)&qrow[quad * 8];
        short8 qa1 = *(const short8*)&qrow[32 + quad * 8];
        float* obase = oout + ((size_t)bh * Tdim + 1024 + tl0) * Vdim;
#pragma unroll
        for (int n = 0; n < 4; ++n) {
            short8 hb0 = *(const short8*)&Hm[(16 * n + r) * LP + quad * 8];
            short8 hb1 = *(const short8*)&Hm[(16 * n + r) * LP + 32 + quad * 8];
            float4_ acc;
#pragma unroll
            for (int reg = 0; reg < 4; ++reg)
                acc[reg] = obase[(quad * 4 + reg) * Vdim + 16 * n + r];
            acc = MFMA(qa0, hb0, acc);
            acc = MFMA(qa1, hb1, acc);
#pragma unroll
            for (int reg = 0; reg < 4; ++reg)
                obase[(quad * 4 + reg) * Vdim + 16 * n + r] = acc[reg];
        }
    }
}

// ---- Kernel C: fin = h_end + e^{sumw} * h_mid ----
__global__ __launch_bounds__(256) void rwkv6_fin(
    const float* __restrict__ hmid, const float* __restrict__ hend,
    const float* __restrict__ sumw, float* __restrict__ fin)
{
    const int bh = blockIdx.x, tid = threadIdx.x;
    for (int i = tid; i < 4096; i += 256) {
        const int v = i >> 6, k = i & 63;
        const float e = __expf(sumw[bh * 64 + k]);
        fin[((size_t)bh * 64 + k) * 64 + v] =
            hend[(size_t)bh * 4096 + i] + e * hmid[(size_t)bh * 4096 + i];
    }
}

extern "C" void kernel_launch(void* const* d_in, const int* in_sizes, int n_in,
                              void* d_out, int out_size, void* d_ws, size_t ws_size,
                              hipStream_t stream) {
    const float* r    = (const float*)d_in[0];
    const float* k    = (const float*)d_in[1];
    const float* v    = (const float*)d_in[2];
    const float* w    = (const float*)d_in[3];
    const float* u    = (const float*)d_in[4];
    const float* init = (const float*)d_in[5];

    float* o   = (float*)d_out;
    float* fin = o + (size_t)Bdim * Hdim * Tdim * Vdim;

    // workspace: Qt (bf16, 16.8 MB) | h_mid (2.1 MB) | h_end (2.1 MB) | sumw (32 KB)
    unsigned short* qtg = (unsigned short*)d_ws;
    const size_t QT_ELEMS = (size_t)Bdim * Hdim * (Tdim / 2) * Kdim;
    float* hmid = (float*)(qtg + QT_ELEMS);
    float* hend = hmid + (size_t)Bdim * Hdim * Kdim * Vdim;
    float* sumw = hend + (size_t)Bdim * Hdim * Kdim * Vdim;

    rwkv6_halves<<<512, 512, 0, stream>>>(r, k, v, w, u, init, o,
                                          qtg, hmid, hend, sumw);
    rwkv6_fix<<<1024, 256, 0, stream>>>(qtg, hmid, o);
    rwkv6_fin<<<128, 256, 0, stream>>>(hmid, hend, sumw, fin);
}